// Round 7
// baseline (250.306 us; speedup 1.0000x reference)
//
#include <hip/hip_runtime.h>

// Laplacian pyramid L1 loss, (32,3,512,512) fp32, 5 levels.
// pyramid(in)-pyramid(tg) == pyramid(in-tg) (linearity) -> one pyramid.
// upsample(conv 4K on zero-stuffed) == polyphase on down:
//   even phase taps (.125,.75,.125), odd phase (.5,.5) per axis.
//
// ROUND-7: L0 via global_load_lds DMA ring (lap0_dma).
// Evidence: L0 pinned at ~90us across 3 structurally different register-
// prefetch configs (R0/R1/R3) while delivered HBM BW varied 1.7-2.5 TB/s
// and VALUBusy ~11% -> not BW-bound, not VALU-bound; the invariant is the
// per-CU VMEM-load->VGPR-return path (~2.8 B/cy/CU observed, 4x below need).
// global_load_lds bypasses the VGPR return entirely (DMA to LDS, counted by
// vmcnt), and frees the U/V bank registers that made depth-2 cost 164 VGPR.
// Structure: R=32 strips, 4 waves/block, 384 blocks (all co-resident,
// LDS 64KB -> 2 blocks/CU). Per-wave 2-slot ring, slot = 4 rows (c1A,c2A,
// c1B,c2B) x 2KB. Per body: s_waitcnt vmcnt(8) (counted: newer-than-slot =
// next slot's 8 loads [+<=1 store] -> 8 is conservative-safe at all edges),
// ds_read 4 rows, compute, store, lgkmcnt(0) WAR fence, refill slot for
// body k+2. DMA mapping is identity: lane L writes slot+16L = row floats
// 4L..4L+3, so LDS holds plain rows; consume = float4 pair at lane*8.
// Tripwires: absmax 0.0; WRITE_SIZE 24.6MB (no spill); LDS_Block_Size ~65KB.
// Falsification: if lap0_dma ~= 90us, bottleneck is L2/L3-side service, not
// the CU return path -> pivot to tail/launch overhead next.
// Tail (lap_rest, verified 243.7us baseline) unchanged from R6.

#define BC 96
#define KA 0.0625f
#define KB 0.25f
#define KC 0.375f

__device__ __forceinline__ int refl(int i, int n) {
    if (i < 0) i = -i;
    if (i >= n) i = 2 * n - 2 - i;
    return i;
}

// raw row load at row r: A into a[], B into b[] (DIFF only). SS = src row stride.
template<int SS, int NC, bool DIFF>
__device__ __forceinline__ void load_raw(const float* __restrict__ pa,
                                         const float* __restrict__ pb,
                                         int r, int basec,
                                         float* __restrict__ a,
                                         float* __restrict__ b) {
    const int off = r * SS + basec;
    if constexpr (NC == 8) {
        float4 a0 = *(const float4*)(pa + off);
        float4 a1 = *(const float4*)(pa + off + 4);
        a[0]=a0.x; a[1]=a0.y; a[2]=a0.z; a[3]=a0.w;
        a[4]=a1.x; a[5]=a1.y; a[6]=a1.z; a[7]=a1.w;
        if constexpr (DIFF) {
            float4 b0 = *(const float4*)(pb + off);
            float4 b1 = *(const float4*)(pb + off + 4);
            b[0]=b0.x; b[1]=b0.y; b[2]=b0.z; b[3]=b0.w;
            b[4]=b1.x; b[5]=b1.y; b[6]=b1.z; b[7]=b1.w;
        }
    } else if constexpr (NC == 4) {
        float4 a0 = *(const float4*)(pa + off);
        a[0]=a0.x; a[1]=a0.y; a[2]=a0.z; a[3]=a0.w;
        if constexpr (DIFF) {
            float4 b0 = *(const float4*)(pb + off);
            b[0]=b0.x; b[1]=b0.y; b[2]=b0.z; b[3]=b0.w;
        }
    } else {
        float2 a0 = *(const float2*)(pa + off);
        a[0]=a0.x; a[1]=a0.y;
        if constexpr (DIFF) {
            float2 b0 = *(const float2*)(pb + off);
            b[0]=b0.x; b[1]=b0.y;
        }
    }
}

template<int NC, bool DIFF>
__device__ __forceinline__ void materialize(const float* __restrict__ a,
                                            const float* __restrict__ b,
                                            float* __restrict__ c) {
#pragma unroll
    for (int i = 0; i < NC; ++i) c[i] = DIFF ? (a[i] - b[i]) : a[i];
}

// horizontal 5-tap at even cols. c = own NC cols; o = ND outputs.
template<int NC>
__device__ __forceinline__ void hconv(const float* __restrict__ c,
                                      float* __restrict__ o, int lane) {
    constexpr int ND = NC / 2;
    float e[NC + 3];
#pragma unroll
    for (int i = 0; i < NC; ++i) e[i + 2] = c[i];
    const bool l0 = (lane == 0), l63 = (lane == 63);
    { float v = __shfl(e[NC + 1], lane - 1); e[1] = l0 ? e[3] : v; }
    if constexpr (NC >= 4) {
        { float v = __shfl(e[NC], lane - 1); e[0] = l0 ? e[4] : v; }
        { float v = __shfl(e[2], lane + 1); e[NC + 2] = l63 ? e[NC] : v; }
    } else {
        e[0] = __shfl(e[2], l0 ? 1 : lane - 1);
        e[NC + 2] = __shfl(e[2], l63 ? 63 : lane + 1);
    }
#pragma unroll
    for (int j = 0; j < ND; ++j)
        o[j] = KA * e[2*j] + KB * e[2*j+1] + KC * e[2*j+2]
             + KB * e[2*j+3] + KA * e[2*j+4];
}

// ---- global_load_lds helpers (L0) ----
// One 1KB half-row: lane L's 16B from g+4L lands at l+16L (wave-uniform l).
__device__ __forceinline__ void dma_half(const float* g, float* l, int lane) {
    __builtin_amdgcn_global_load_lds(
        (__attribute__((address_space(1))) const void*)(g + 4 * lane),
        (__attribute__((address_space(3))) void*)(l), 16, 0, 0);
}
__device__ __forceinline__ void dma_row512(const float* g, float* l, int lane) {
    dma_half(g, l, lane);
    dma_half(g + 256, l + 256, lane);
}
// slot fill = 8 gload_lds instrs: rows r1,r2 of A then of B.
__device__ __forceinline__ void dma_slot(const float* pa, const float* pb,
                                         int r1, int r2, float* slot, int lane) {
    dma_row512(pa + (size_t)r1 * 512, slot + 0 * 512, lane);
    dma_row512(pa + (size_t)r2 * 512, slot + 1 * 512, lane);
    dma_row512(pb + (size_t)r1 * 512, slot + 2 * 512, lane);
    dma_row512(pb + (size_t)r2 * 512, slot + 3 * 512, lane);
}
__device__ __forceinline__ void lds_row8(const float* l, int lane, float* c) {
    const float4 x = *(const float4*)(l + lane * 8);
    const float4 y = *(const float4*)(l + lane * 8 + 4);
    c[0]=x.x; c[1]=x.y; c[2]=x.z; c[3]=x.w;
    c[4]=y.x; c[5]=y.y; c[6]=y.z; c[7]=y.w;
}

// ---- level 0: DMA-ring slide. 4 waves/block, R=32 strips, 384 blocks ----
__global__ __launch_bounds__(256) void lap0_dma(
        const float* __restrict__ A, const float* __restrict__ B,
        float* __restrict__ down, float* __restrict__ out, float invN) {
    constexpr int H = 512, Hd = 256, R = 32, SPP = H / R;   // SPP=16
    constexpr int NB = R / 2 + 2;                           // 18 bodies
    __shared__ float ring[4][2][4][512];                    // 64 KB
    __shared__ float red[4];
    const int tid = threadIdx.x;
    const int lane = tid & 63, wid = tid >> 6;
    const int sid = blockIdx.x * 4 + wid;
    const int bc = sid / SPP;
    const int y0 = (sid % SPP) * R;
    const float* pa = A + (size_t)bc * H * H;
    const float* pb = B + (size_t)bc * H * H;
    float* pd = down + (size_t)bc * Hd * Hd;
    float* slot0 = &ring[wid][0][0][0];
    float* slot1 = &ring[wid][1][0][0];
    const int basec = lane * 8;

    const int d0 = y0 >> 1;
    const int db = d0 - 1;   // uniform start (reflection makes W[-1]=W[1])

    float h0[4], h1[4], h2[4], h3[4], h4[4];
    float wPrev[8], pA[8], pB[8], pC[8];
#pragma unroll
    for (int i = 0; i < 8; ++i) { wPrev[i]=0.f; pA[i]=0.f; pB[i]=0.f; pC[i]=0.f; }
    float acc = 0.f;

    // prologue h-ring: rows 2db-2, 2db-1, 2db (direct VGPR loads, 3 rounds)
    {
        float t[8], tb[8], c[8];
        load_raw<H,8,true>(pa, pb, refl(2*db - 2, H), basec, t, tb);
        materialize<8,true>(t, tb, c); hconv<8>(c, h0, lane);
        load_raw<H,8,true>(pa, pb, refl(2*db - 1, H), basec, t, tb);
        materialize<8,true>(t, tb, c); hconv<8>(c, h1, lane);
        load_raw<H,8,true>(pa, pb, refl(2*db, H), basec, t, tb);
        materialize<8,true>(t, tb, c); hconv<8>(c, h2, lane);
    }
    // prologue DMA: slots for bodies 0 and 1
    dma_slot(pa, pb, refl(2*db + 1, H), refl(2*db + 2, H), slot0, lane);
    dma_slot(pa, pb, refl(2*db + 3, H), refl(2*db + 4, H), slot1, lane);

#pragma unroll
    for (int k = 0; k < NB; ++k) {
        const int d = db + k;
        float* slot = (k & 1) ? slot1 : slot0;

        // Wait for this body's slot. Newer-than-target ops = next slot's 8
        // loads (+<=1 down-store) -> vmcnt(8) is exact/conservative always.
        asm volatile("s_waitcnt vmcnt(8)" ::: "memory");

        float a1[8], a2[8], b1[8], b2[8], c1[8], c2[8];
        lds_row8(slot + 0 * 512, lane, a1);
        lds_row8(slot + 1 * 512, lane, a2);
        lds_row8(slot + 2 * 512, lane, b1);
        lds_row8(slot + 3 * 512, lane, b2);
#pragma unroll
        for (int i = 0; i < 8; ++i) { c1[i] = a1[i] - b1[i]; c2[i] = a2[i] - b2[i]; }

        hconv<8>(c1, h3, lane);
        hconv<8>(c2, h4, lane);

        float dn[4];
#pragma unroll
        for (int j = 0; j < 4; ++j)
            dn[j] = KA*h0[j] + KB*h1[j] + KC*h2[j] + KB*h3[j] + KA*h4[j];

        if (k >= 1 && k < 1 + R/2) {   // store down rows d in [d0, d0+R/2)
            const int doff = d * Hd + lane * 4;
            float4 s; s.x=dn[0]; s.y=dn[1]; s.z=dn[2]; s.w=dn[3];
            *(float4*)(pd + doff) = s;
        }

        // horizontal-up row W[d] -> wN
        float dm, dp;
        { float v = __shfl(dn[3], lane - 1); dm = (lane == 0)  ? dn[1] : v; }
        { float v = __shfl(dn[0], lane + 1); dp = (lane == 63) ? dn[3] : v; }
        float wN[8];
#pragma unroll
        for (int j = 0; j < 4; ++j) {
            float lf = j ? dn[j-1] : dm;
            float rg = (j + 1 < 4) ? dn[j+1] : dp;
            wN[2*j]     = 0.125f * lf + 0.75f * dn[j] + 0.125f * rg;
            wN[2*j + 1] = 0.5f * (dn[j] + rg);
        }

        // finalize band rows 2d-2 (even, pA) and 2d-1 (odd, pB)
        if (k >= 2) {
#pragma unroll
            for (int i = 0; i < 8; ++i) {
                acc += fabsf(pA[i] - (0.75f*wPrev[i] + 0.125f*wN[i]));
                acc += fabsf(pB[i] - 0.5f*wN[i]);
            }
        }

        // create next pending state + shift rings
#pragma unroll
        for (int i = 0; i < 8; ++i) {
            pA[i] = pC[i];
            pC[i] = c2[i] - 0.125f * wN[i];   // even row 2d+2 - 0.125*W[d]
            pB[i] = c1[i] - 0.5f   * wN[i];   // odd  row 2d+1 - 0.5*W[d]
            wPrev[i] = wN[i];
        }
#pragma unroll
        for (int j = 0; j < 4; ++j) { h0[j] = h2[j]; h1[j] = h3[j]; h2[j] = h4[j]; }

        // refill this slot for body k+2 (WAR: ds_reads must be retired)
        if (k < NB - 2) {
            asm volatile("s_waitcnt lgkmcnt(0)" ::: "memory");
            dma_slot(pa, pb, refl(2*d + 5, H), refl(2*d + 6, H), slot, lane);
        }
    }

#pragma unroll
    for (int off2 = 32; off2 > 0; off2 >>= 1)
        acc += __shfl_down(acc, off2, 64);
    if (lane == 0) red[wid] = acc;
    __syncthreads();
    if (tid == 0)
        atomicAdd(out, (red[0] + red[1] + red[2] + red[3]) * invN);
}

// One R-row strip of one level: band L1-sum returned; down rows written to
// pd (row stride DS). Verified algebra (R3/R4, absmax 0). PD = prefetch depth.
template<int H, int NC, int R, int SS, int DS, bool DIFF, int PD>
__device__ __forceinline__ float slide_strip(
        const float* __restrict__ pa, const float* __restrict__ pb,
        float* __restrict__ pd, int lane, int y0) {
    constexpr int ND = NC / 2;
    const int basec = lane * NC;

    float h0[ND], h1[ND], h2[ND], h3[ND], h4[ND];
    float wPrev[NC], pA[NC], pB[NC], pC[NC];  // pending band state
    float UA1[NC], UA2[NC];                   // prefetch bank U
    float UB1[DIFF ? NC : 1], UB2[DIFF ? NC : 1];
    float VA1[PD == 2 ? NC : 1], VA2[PD == 2 ? NC : 1];  // bank V (PD=2)
    float VB1[(PD == 2 && DIFF) ? NC : 1], VB2[(PD == 2 && DIFF) ? NC : 1];
#pragma unroll
    for (int i = 0; i < NC; ++i) {
        wPrev[i] = 0.f; pA[i] = 0.f; pB[i] = 0.f; pC[i] = 0.f;
    }
    float acc = 0.f;

    const int d0 = y0 >> 1;
    const int db = d0 - 1;   // uniform start (reflection makes W[-1]=W[1])

    // prologue: h-ring rows 2db-2, 2db-1, 2db
    {
        float t[NC], tb[DIFF ? NC : 1], c[NC];
        load_raw<SS,NC,DIFF>(pa, pb, refl(2*db - 2, H), basec, t, tb);
        materialize<NC,DIFF>(t, tb, c); hconv<NC>(c, h0, lane);
        load_raw<SS,NC,DIFF>(pa, pb, refl(2*db - 1, H), basec, t, tb);
        materialize<NC,DIFF>(t, tb, c); hconv<NC>(c, h1, lane);
        load_raw<SS,NC,DIFF>(pa, pb, refl(2*db, H), basec, t, tb);
        materialize<NC,DIFF>(t, tb, c); hconv<NC>(c, h2, lane);
    }
    // fill banks: U <- rows for first body (and V <- second, PD=2)
    load_raw<SS,NC,DIFF>(pa, pb, refl(2*db + 1, H), basec, UA1, UB1);
    load_raw<SS,NC,DIFF>(pa, pb, refl(2*db + 2, H), basec, UA2, UB2);
    if constexpr (PD == 2) {
        load_raw<SS,NC,DIFF>(pa, pb, refl(2*db + 3, H), basec, VA1, VB1);
        load_raw<SS,NC,DIFF>(pa, pb, refl(2*db + 4, H), basec, VA2, VB2);
    }

    // one iteration body. Bank consumed here was loaded PD bodies ago.
    auto body = [&](int d, float* A1, float* A2, float* B1, float* B2,
                    bool doFin, bool doStore, bool doIssue) {
        float c1[NC], c2[NC];
        materialize<NC,DIFF>(A1, B1, c1);   // raw row 2d+1
        materialize<NC,DIFF>(A2, B2, c2);   // raw row 2d+2
        if (doIssue) {                      // refill for iter d+PD
            load_raw<SS,NC,DIFF>(pa, pb, refl(2*d + 2*PD + 1, H), basec, A1, B1);
            load_raw<SS,NC,DIFF>(pa, pb, refl(2*d + 2*PD + 2, H), basec, A2, B2);
        }
        hconv<NC>(c1, h3, lane);
        hconv<NC>(c2, h4, lane);

        float dn[ND];
#pragma unroll
        for (int j = 0; j < ND; ++j)
            dn[j] = KA*h0[j] + KB*h1[j] + KC*h2[j] + KB*h3[j] + KA*h4[j];

        if (doStore) {
            const int doff = d * DS + lane * ND;
            if constexpr (ND == 4) {
                float4 s; s.x=dn[0]; s.y=dn[1]; s.z=dn[2]; s.w=dn[3];
                *(float4*)(pd + doff) = s;
            } else if constexpr (ND == 2) {
                float2 s; s.x=dn[0]; s.y=dn[1];
                *(float2*)(pd + doff) = s;
            } else {
                pd[doff] = dn[0];
            }
        }

        // horizontal-up row W[d] -> wN
        float dm, dp;
        if constexpr (ND >= 2) {
            { float v = __shfl(dn[ND-1], lane - 1); dm = (lane == 0)  ? dn[1]    : v; }
            { float v = __shfl(dn[0],    lane + 1); dp = (lane == 63) ? dn[ND-1] : v; }
        } else {
            dm = __shfl(dn[0], (lane == 0)  ? 1  : lane - 1);
            dp = __shfl(dn[0], (lane == 63) ? 63 : lane + 1);
        }
        float wN[NC];
#pragma unroll
        for (int j = 0; j < ND; ++j) {
            float lf = j ? dn[j-1] : dm;
            float rg = (j + 1 < ND) ? dn[j+1] : dp;
            wN[2*j]     = 0.125f * lf + 0.75f * dn[j] + 0.125f * rg;
            wN[2*j + 1] = 0.5f * (dn[j] + rg);
        }

        // finalize band rows 2d-2 (even, pA) and 2d-1 (odd, pB).
        if (doFin) {
#pragma unroll
            for (int i = 0; i < NC; ++i) {
                acc += fabsf(pA[i] - (0.75f*wPrev[i] + 0.125f*wN[i]));
                acc += fabsf(pB[i] - 0.5f*wN[i]);
            }
        }

        // create next pending state + shift rings
#pragma unroll
        for (int i = 0; i < NC; ++i) {
            pA[i] = pC[i];
            pC[i] = c2[i] - 0.125f * wN[i];   // even row 2d+2 - 0.125*W[d]
            pB[i] = c1[i] - 0.5f   * wN[i];   // odd  row 2d+1 - 0.5*W[d]
            wPrev[i] = wN[i];
        }
#pragma unroll
        for (int j = 0; j < ND; ++j) { h0[j] = h2[j]; h1[j] = h3[j]; h2[j] = h4[j]; }
    };

    if constexpr (PD == 1) {
        // bodies k=0..R/2+1, d = db+k
#pragma unroll
        for (int k = 0; k < R/2 + 2; ++k) {
            body(db + k, UA1, UA2, UB1, UB2,
                 k >= 2,                 // fin: d >= d0+1
                 k >= 1 && k < R/2 + 1,  // store: d in [d0, d0+R/2)
                 k < R/2 + 1);           // issue: d < dend
        }
    } else {
        constexpr int CNT2 = R / 4 + 1;
#pragma unroll
        for (int i = 0; i < CNT2; ++i) {
            const bool fin = (i >= 1);
            const bool iss = (i < CNT2 - 1);
            body(db + 2*i,     UA1, UA2, UB1, UB2, fin, i >= 1,       iss);
            body(db + 2*i + 1, VA1, VA2, VB1, VB2, fin, i < CNT2 - 1, iss);
        }
    }
    return acc;
}

// ---- levels 1..4 fused: one 1024-thr block per plane ----
__global__ __launch_bounds__(1024) void lap_rest(
        const float* __restrict__ down0, float* __restrict__ out,
        float invN1, float invN2, float invN3, float invN4) {
    __shared__ float d1[128 * 128];   // down1 (level-1 output)
    __shared__ float p[64 * 66];      // down2, padded (lap_small layout)
    __shared__ float hh[64 * 34];
    __shared__ float dd[32 * 34];
    __shared__ float W3[32 * 64];
    __shared__ float h4[32 * 18];
    __shared__ float d4[16 * 18];
    __shared__ float W4[16 * 32];
    __shared__ float red[16];
    const int tid = threadIdx.x;
    const int lane = tid & 63, wid = tid >> 6;   // 16 waves
    const float* src = down0 + (size_t)blockIdx.x * 65536;

    // L1: H=256, NC=4, R=16 strips; src global (stride 256) -> d1 (stride 128)
    float acc = invN1 *
        slide_strip<256, 4, 16, 256, 128, false, 1>(src, nullptr, d1, lane, wid * 16);
    __syncthreads();
    // L2: H=128, NC=2, R=8 strips; src d1 (stride 128) -> p (stride 66, ND=1)
    acc += invN2 *
        slide_strip<128, 2, 8, 128, 66, false, 1>(d1, nullptr, p, lane, wid * 8);
    __syncthreads();

    // L3/L4: verified lap_small code on p
    const float k[5] = {KA, KB, KC, KB, KA};
    for (int i = tid; i < 64 * 32; i += 1024) {
        int r = i >> 5, t = i & 31;
        const float* pr = p + r * 66;
        float s = 0.f;
#pragma unroll
        for (int v = 0; v < 5; ++v) s += k[v] * pr[refl(2*t + v - 2, 64)];
        hh[r * 34 + t] = s;
    }
    __syncthreads();
    for (int i = tid; i < 32 * 32; i += 1024) {
        int dy = i >> 5, t = i & 31;
        float s = 0.f;
#pragma unroll
        for (int u = 0; u < 5; ++u) s += k[u] * hh[refl(2*dy + u - 2, 64) * 34 + t];
        dd[dy * 34 + t] = s;
    }
    __syncthreads();
    for (int i = tid; i < 32 * 32; i += 1024) {
        int a = i >> 5, t = i & 31;
        const float* dr = dd + a * 34;
        float dm = dr[t == 0 ? 1 : t - 1];
        float dc = dr[t];
        float dp = dr[t == 31 ? 31 : t + 1];
        W3[a * 64 + 2*t]     = 0.125f * dm + 0.75f * dc + 0.125f * dp;
        W3[a * 64 + 2*t + 1] = 0.5f * (dc + dp);
    }
    __syncthreads();
    float acc3 = 0.f;
    for (int i = tid; i < 4096; i += 1024) {
        int y = i >> 6, x = i & 63;
        float cur = p[y * 66 + x];
        float up;
        if ((y & 1) == 0) {
            int a0 = refl(y - 2, 64) >> 1, a1 = y >> 1, a2 = refl(y + 2, 64) >> 1;
            up = 0.125f*W3[a0*64 + x] + 0.75f*W3[a1*64 + x] + 0.125f*W3[a2*64 + x];
        } else {
            int a0 = (y - 1) >> 1, a1 = refl(y + 1, 64) >> 1;
            up = 0.5f * (W3[a0*64 + x] + W3[a1*64 + x]);
        }
        acc3 += fabsf(cur - up);
    }
    __syncthreads();
    for (int i = tid; i < 32 * 16; i += 1024) {
        int r = i >> 4, t = i & 15;
        const float* pr = dd + r * 34;
        float s = 0.f;
#pragma unroll
        for (int v = 0; v < 5; ++v) s += k[v] * pr[refl(2*t + v - 2, 32)];
        h4[r * 18 + t] = s;
    }
    __syncthreads();
    for (int i = tid; i < 16 * 16; i += 1024) {
        int dy = i >> 4, t = i & 15;
        float s = 0.f;
#pragma unroll
        for (int u = 0; u < 5; ++u) s += k[u] * h4[refl(2*dy + u - 2, 32) * 18 + t];
        d4[dy * 18 + t] = s;
    }
    __syncthreads();
    for (int i = tid; i < 16 * 16; i += 1024) {
        int a = i >> 4, t = i & 15;
        const float* dr = d4 + a * 18;
        float dm = dr[t == 0 ? 1 : t - 1];
        float dc = dr[t];
        float dp = dr[t == 15 ? 15 : t + 1];
        W4[a * 32 + 2*t]     = 0.125f * dm + 0.75f * dc + 0.125f * dp;
        W4[a * 32 + 2*t + 1] = 0.5f * (dc + dp);
    }
    __syncthreads();
    float acc4 = 0.f;
    for (int i = tid; i < 1024; i += 1024) {
        int y = i >> 5, x = i & 31;
        float cur = dd[y * 34 + x];
        float up;
        if ((y & 1) == 0) {
            int a0 = refl(y - 2, 32) >> 1, a1 = y >> 1, a2 = refl(y + 2, 32) >> 1;
            up = 0.125f*W4[a0*32 + x] + 0.75f*W4[a1*32 + x] + 0.125f*W4[a2*32 + x];
        } else {
            int a0 = (y - 1) >> 1, a1 = refl(y + 1, 32) >> 1;
            up = 0.5f * (W4[a0*32 + x] + W4[a1*32 + x]);
        }
        acc4 += fabsf(cur - up);
    }
    acc += acc3 * invN3 + acc4 * invN4;

#pragma unroll
    for (int off2 = 32; off2 > 0; off2 >>= 1)
        acc += __shfl_down(acc, off2, 64);
    if (lane == 0) red[wid] = acc;
    __syncthreads();
    if (tid == 0) {
        float s = 0.f;
#pragma unroll
        for (int i = 0; i < 16; ++i) s += red[i];
        atomicAdd(out, s);
    }
}

extern "C" void kernel_launch(void* const* d_in, const int* in_sizes, int n_in,
                              void* d_out, int out_size, void* d_ws, size_t ws_size,
                              hipStream_t stream) {
    const float* in = (const float*)d_in[0];
    const float* tg = (const float*)d_in[1];
    float* out = (float*)d_out;
    float* ws = (float*)d_ws;

    float* down0 = ws;   // 96*256*256 floats

    hipMemsetAsync(out, 0, sizeof(float), stream);

    // level 0: DMA ring, R=32 -> 96*16 strips / 4 waves = 384 blocks
    lap0_dma<<<96 * 16 / 4, 256, 0, stream>>>(
        in, tg, down0, out, 1.f / (96.f * 512.f * 512.f));
    // levels 1-4 fused: one block per plane (verified R6 baseline)
    lap_rest<<<BC, 1024, 0, stream>>>(
        down0, out,
        1.f / (96.f * 256.f * 256.f), 1.f / (96.f * 128.f * 128.f),
        1.f / (96.f * 64.f * 64.f),  1.f / (96.f * 32.f * 32.f));
}